// Round 4
// baseline (769.933 us; speedup 1.0000x reference)
//
#include <hip/hip_runtime.h>
#include <hip/hip_fp16.h>
#include <cstdint>
#include <cstddef>

#define B_   4
#define T_   4096
#define D_   2560
#define H_   10
#define BW   256
#define NROWS (B_*T_)   // 16384
#define CCH  64         // number of chunks along T
#define LCH  64         // chunk length (CCH*LCH == T_)
#define DG   (D_/256)   // 10 d-groups of 256 cols
#define NUNIT (B_*CCH*DG)   // 2560 scan units
#define USTRIDE (B_*DG)     // 40 units per chunk-level (all c-1 tickets < c tickets)

typedef short s16x8 __attribute__((ext_vector_type(8)));
typedef float f32x4 __attribute__((ext_vector_type(4)));

__device__ __forceinline__ unsigned short f2bf(float f) {
  union { float f; uint32_t u; } v; v.f = f;
  uint32_t u = v.u;
  u += 0x7fffu + ((u >> 16) & 1u);   // round-to-nearest-even
  return (unsigned short)(u >> 16);
}

// async 16B global->LDS copy (per-lane global src, wave-uniform LDS base + lane*16)
__device__ __forceinline__ void async_copy16(const unsigned short* g, unsigned short* l) {
  __builtin_amdgcn_global_load_lds(
      (const __attribute__((address_space(1))) unsigned int*)g,
      (__attribute__((address_space(3))) unsigned int*)l,
      16, 0, 0);
}

// ---------------- prep: transpose+cast weights to bf16 [H][512][256] (n-major,
// k-contiguous, n<256 = ig cols, n>=256 = rg cols), and softplus(recurrent_param)
__global__ __launch_bounds__(256) void prep_kernel(
    const float* __restrict__ igw, const float* __restrict__ rgw,
    const float* __restrict__ rp,
    unsigned short* __restrict__ wt, float* __restrict__ sp) {
  int idx = blockIdx.x * 256 + threadIdx.x;
  const int total = H_ * 512 * 256;
  if (idx < total) {
    int k = idx & 255;
    int n = (idx >> 8) & 511;
    int h = idx >> 17;
    float w = (n < 256) ? igw[(h*BW + k)*BW + n]
                        : rgw[(h*BW + k)*BW + (n - 256)];
    wt[idx] = f2bf(w);
  }
  if (idx < D_) {
    float z = rp[idx];
    sp[idx] = fmaxf(z, 0.0f) + log1pf(__expf(-fabsf(z)));
  }
}

// Stage one 64KB B-chunk into LDS with 8 waves: chunk g (0..3) covers ig cols
// [g*64,g*64+64) (lds n 0..63) and rg cols [256+g*64,+64) (lds n 64..127), k=256
// bf16, XOR-swizzled: lds[n*512 + (kb ^ ((n&7)<<4))] = w[col(n)][kb]. The global
// source carries the same XOR so global_load_lds's linear lane*16 write lands right.
__device__ __forceinline__ void stage_chunk(const unsigned short* __restrict__ wth,
                                            unsigned short* Bsm,
                                            int wave, int lane, int g) {
  #pragma unroll
  for (int i = 0; i < 8; ++i) {
    const int ob = wave * 8192 + i * 1024;    // wave-uniform LDS byte base (1KB/call)
    const int o  = ob + lane * 16;            // this lane's LDS byte slot
    const int n  = o >> 9;                    // 0..127
    const int nm = n + ((n < 64) ? g * 64 : 192 + g * 64);  // global weight col
    const int sb = (o & 511) ^ ((n & 7) << 4);              // swizzled k-byte
    async_copy16(wth + (size_t)nm * 256 + (sb >> 1), Bsm + (ob >> 1));
  }
}

// ---------------- gates: block = 8 waves x 16 rows = 128 rows, one head.
// 4 column-chunks of (64 ig | 64 rg); each 64KB B-tile staged in LDS, shared by
// 8 waves. Per-wave regs: A[8]=32 + acc[8]=32 + temps ~= 95 VGPR -> fits the
// 128 cap of launch_bounds(512,4) WITHOUT spilling (r3 lesson: 2mt needed ~130).
// 2 blocks/CU (LDS-capped) x 8 waves = 16 waves/CU.
// MFMA 16x16x32 bf16. A-frag: A[m=lane&15][k=quad*8+j]; B-frag: B[k=quad*8+j][n=lane&15];
// C/D: col=lane&15, row=quad*4+r.
__global__ __launch_bounds__(512, 4) void gates_kernel(
    const float* __restrict__ act, const int* __restrict__ pos,
    const float* __restrict__ igb, const float* __restrict__ rgb,
    const unsigned short* __restrict__ wt, const float* __restrict__ sp,
    __half2* __restrict__ ax) {
  __shared__ unsigned short Bsm[32768];   // 64 KB
  const int h    = blockIdx.y;
  const int wave = threadIdx.x >> 6;
  const int lane = threadIdx.x & 63;
  const int l15  = lane & 15;
  const int quad = lane >> 4;
  const int m0w  = blockIdx.x * 128 + wave * 16;
  const int hd   = h * BW;
  const unsigned short* wth = wt + (size_t)h * 512 * 256;

  // ---- A fragments: 16 rows x 256 k, register-resident all kernel (32 VGPR)
  s16x8 A[8];
  {
    const float* ar = act + (size_t)(m0w + l15) * D_ + hd;
    #pragma unroll
    for (int kt = 0; kt < 8; ++kt) {
      const int ko = kt * 32 + quad * 8;
      f32x4 f0 = *(const f32x4*)(ar + ko);
      f32x4 f1 = *(const f32x4*)(ar + ko + 4);
      s16x8 af;
      af[0] = (short)f2bf(f0[0]); af[1] = (short)f2bf(f0[1]);
      af[2] = (short)f2bf(f0[2]); af[3] = (short)f2bf(f0[3]);
      af[4] = (short)f2bf(f1[0]); af[5] = (short)f2bf(f1[1]);
      af[6] = (short)f2bf(f1[2]); af[7] = (short)f2bf(f1[3]);
      A[kt] = af;
    }
  }

  bool rst[4];
  #pragma unroll
  for (int r = 0; r < 4; ++r)
    rst[r] = (pos[m0w + quad * 4 + r] == 0);

  stage_chunk(wth, Bsm, wave, lane, 0);

  for (int g = 0; g < 4; ++g) {
    __syncthreads();   // staging of chunk g complete (vmcnt drained + barrier)

    f32x4 acc[8];
    #pragma unroll
    for (int nq = 0; nq < 8; ++nq) acc[nq] = (f32x4){0.f, 0.f, 0.f, 0.f};

    #pragma unroll
    for (int kt = 0; kt < 8; ++kt) {
      #pragma unroll
      for (int nq = 0; nq < 8; ++nq) {
        const int bo = ((nq * 16 + l15) << 9) +
                       (((kt << 6) + (quad << 4)) ^ ((l15 & 7) << 4));
        const s16x8 bf = *(const s16x8*)((const char*)Bsm + bo);
        acc[nq] = __builtin_amdgcn_mfma_f32_16x16x32_bf16(A[kt], bf, acc[nq], 0, 0, 0);
      }
    }

    __syncthreads();   // all waves done reading chunk g
    if (g < 3) stage_chunk(wth, Bsm, wave, lane, g + 1);   // async prefetch

    // epilogue for this 64-col chunk overlaps the async staging above.
    // nq 0..3 = ig accumulators, nq 4..7 = matching rg accumulators (same d).
    #pragma unroll
    for (int nqp = 0; nqp < 4; ++nqp) {
      const int d = hd + g * 64 + nqp * 16 + l15;
      const float bi  = igb[d];
      const float br  = rgb[d];
      const float spd = sp[d];
      #pragma unroll
      for (int r = 0; r < 4; ++r) {
        const int row = m0w + quad * 4 + r;
        const float ig_logit = acc[nqp][r]     + bi;
        const float rg_logit = acc[nqp + 4][r] + br;
        const float igate = 1.0f / (1.0f + __expf(-ig_logit));
        const float rgate = 1.0f / (1.0f + __expf(-rg_logit));
        const float a     = __expf(-8.0f * rgate * spd);
        const bool  rs    = rst[r];
        const float a_eff = rs ? 0.0f : a;
        const float mult  = rs ? 1.0f : sqrtf(fmaxf(1.0f - a * a, 0.0f));
        const float xv    = act[(size_t)row * D_ + d];
        const float xo    = xv * igate * mult;
        ax[(size_t)row * D_ + d] = __float22half2_rn(make_float2(a_eff, xo));
      }
    }
  }
}

// ---------------- single-pass scan via decoupled lookback.
// Each block: ticket -> unit (c, b, dgrp) with ascending-c ticket order
// (dispatch order == ticket order => all predecessors already started =>
// deadlock-free). Local scan holds the 64 (a,x) half2 in registers (static
// indices, fully unrolled). Publish aggregate (P,X) [status 1], compose
// predecessors' aggregates until an inclusive prefix [status 2] is found,
// publish own inclusive, replay from registers, write out. ax read ONCE.
// All cross-block data via agent-scope atomics (per-XCD L2s not coherent).
__global__ __launch_bounds__(256) void scan_kernel(
    const __half2* __restrict__ ax, float* __restrict__ out,
    float* __restrict__ Pb, float* __restrict__ Xb, float* __restrict__ Hb,
    int* __restrict__ flags, int* __restrict__ ticket) {
  __shared__ int s_vuid;
  __shared__ int s_flag;
  if (threadIdx.x == 0) s_vuid = atomicAdd(ticket, 1);
  __syncthreads();
  const int vuid = s_vuid;
  const int c    = vuid / USTRIDE;
  const int rem  = vuid % USTRIDE;
  const int b    = rem / DG;
  const int dgrp = rem % DG;
  const int d    = dgrp * 256 + threadIdx.x;
  const int slot = (vuid << 8) + threadIdx.x;
  const size_t base = ((size_t)b * T_ + (size_t)c * LCH) * D_ + d;

  // ---- local scan, values held in registers (64 VGPR)
  __half2 v[LCH];
  float P = 1.f, X = 0.f;
  #pragma unroll
  for (int t = 0; t < LCH; ++t) {
    v[t] = ax[base + (size_t)t * D_];
    const float2 f = __half22float2(v[t]);
    X = fmaf(f.x, X, f.y);
    P *= f.x;
  }

  float carry;
  if (c == 0) {
    carry = 0.f;
    __hip_atomic_store(&Hb[slot], X, __ATOMIC_RELAXED, __HIP_MEMORY_SCOPE_AGENT);
    __syncthreads();   // drains stores before flag release
    if (threadIdx.x == 0)
      __hip_atomic_store(&flags[vuid], 2, __ATOMIC_RELEASE, __HIP_MEMORY_SCOPE_AGENT);
  } else {
    // publish aggregate
    __hip_atomic_store(&Pb[slot], P, __ATOMIC_RELAXED, __HIP_MEMORY_SCOPE_AGENT);
    __hip_atomic_store(&Xb[slot], X, __ATOMIC_RELAXED, __HIP_MEMORY_SCOPE_AGENT);
    __syncthreads();
    if (threadIdx.x == 0)
      __hip_atomic_store(&flags[vuid], 1, __ATOMIC_RELEASE, __HIP_MEMORY_SCOPE_AGENT);

    // lookback: compose predecessors backward
    float Pacc = 1.f, Xacc = 0.f;
    int uj = vuid - USTRIDE;
    for (;;) {
      if (threadIdx.x == 0) {
        int f;
        do {
          f = __hip_atomic_load(&flags[uj], __ATOMIC_ACQUIRE, __HIP_MEMORY_SCOPE_AGENT);
        } while (f == 0);
        s_flag = f;
      }
      __syncthreads();
      const int f  = s_flag;
      const int js = (uj << 8) + (int)threadIdx.x;
      if (f == 2) {
        const float Hj = __hip_atomic_load(&Hb[js], __ATOMIC_RELAXED, __HIP_MEMORY_SCOPE_AGENT);
        carry = fmaf(Pacc, Hj, Xacc);
        break;
      } else {
        const float Pj = __hip_atomic_load(&Pb[js], __ATOMIC_RELAXED, __HIP_MEMORY_SCOPE_AGENT);
        const float Xj = __hip_atomic_load(&Xb[js], __ATOMIC_RELAXED, __HIP_MEMORY_SCOPE_AGENT);
        Xacc = fmaf(Pacc, Xj, Xacc);
        Pacc *= Pj;
        uj -= USTRIDE;
      }
      __syncthreads();   // protect s_flag reuse across iterations
    }

    // publish inclusive prefix
    const float Hc = fmaf(P, carry, X);
    __hip_atomic_store(&Hb[slot], Hc, __ATOMIC_RELAXED, __HIP_MEMORY_SCOPE_AGENT);
    __syncthreads();
    if (threadIdx.x == 0)
      __hip_atomic_store(&flags[vuid], 2, __ATOMIC_RELEASE, __HIP_MEMORY_SCOPE_AGENT);
  }

  // ---- replay from registers, write output
  float hv = carry;
  #pragma unroll
  for (int t = 0; t < LCH; ++t) {
    const float2 f = __half22float2(v[t]);
    hv = fmaf(f.x, hv, f.y);
    out[base + (size_t)t * D_] = hv;
  }
}

extern "C" void kernel_launch(void* const* d_in, const int* in_sizes, int n_in,
                              void* d_out, int out_size, void* d_ws, size_t ws_size,
                              hipStream_t stream) {
  const float* act = (const float*)d_in[0];
  const int*   pos = (const int*)d_in[1];
  const float* igw = (const float*)d_in[2];
  const float* igb = (const float*)d_in[3];
  const float* rgw = (const float*)d_in[4];
  const float* rgb = (const float*)d_in[5];
  const float* rp  = (const float*)d_in[6];
  float* out = (float*)d_out;

  char* ws = (char*)d_ws;
  __half2* ax = (__half2*)ws;               ws += (size_t)B_ * T_ * D_ * 4;
  unsigned short* wt = (unsigned short*)ws; ws += (size_t)H_ * 512 * 256 * 2;
  float* sp = (float*)ws;                   ws += 4096;                      // D_*4 padded
  float* Pb = (float*)ws;                   ws += (size_t)NUNIT * 256 * 4;
  float* Xb = (float*)ws;                   ws += (size_t)NUNIT * 256 * 4;
  float* Hb = (float*)ws;                   ws += (size_t)NUNIT * 256 * 4;
  int* flags = (int*)ws;                    ws += (size_t)(NUNIT + 64) * 4;
  int* ticket = flags + NUNIT;

  // reset lookback state each launch (graph-capturable async op)
  hipMemsetAsync(flags, 0, (size_t)(NUNIT + 64) * 4, stream);
  prep_kernel<<<dim3((H_ * 512 * 256 + 255) / 256), 256, 0, stream>>>(igw, rgw, rp, wt, sp);
  gates_kernel<<<dim3(NROWS / 128, H_), 512, 0, stream>>>(act, pos, igb, rgb, wt, sp, ax);
  scan_kernel<<<dim3(NUNIT), 256, 0, stream>>>(ax, out, Pb, Xb, Hb, flags, ticket);
}

// Round 5
// 553.136 us; speedup vs baseline: 1.3919x; 1.3919x over previous
//
#include <hip/hip_runtime.h>
#include <hip/hip_fp16.h>
#include <cstdint>
#include <cstddef>

#define B_   4
#define T_   4096
#define D_   2560
#define H_   10
#define BW   256
#define NROWS (B_*T_)   // 16384
#define CCH  64         // number of chunks along T
#define LCH  64         // chunk length (CCH*LCH == T_)
#define DHALF (D_/2)    // 1280 half2-pairs per row
#define DGK  (DHALF/256) // 5 d-groups of 256 pairs (512 scalars)

typedef short s16x8 __attribute__((ext_vector_type(8)));
typedef float f32x4 __attribute__((ext_vector_type(4)));

__device__ __forceinline__ unsigned short f2bf(float f) {
  union { float f; uint32_t u; } v; v.f = f;
  uint32_t u = v.u;
  u += 0x7fffu + ((u >> 16) & 1u);   // round-to-nearest-even
  return (unsigned short)(u >> 16);
}

// async 16B global->LDS copy (per-lane global src, wave-uniform LDS base + lane*16)
__device__ __forceinline__ void async_copy16(const unsigned short* g, unsigned short* l) {
  __builtin_amdgcn_global_load_lds(
      (const __attribute__((address_space(1))) unsigned int*)g,
      (__attribute__((address_space(3))) unsigned int*)l,
      16, 0, 0);
}

// ---------------- prep: transpose+cast weights to bf16 [H][512][256] (n-major,
// k-contiguous, n<256 = ig cols, n>=256 = rg cols), and softplus(recurrent_param)
__global__ __launch_bounds__(256) void prep_kernel(
    const float* __restrict__ igw, const float* __restrict__ rgw,
    const float* __restrict__ rp,
    unsigned short* __restrict__ wt, float* __restrict__ sp) {
  int idx = blockIdx.x * 256 + threadIdx.x;
  const int total = H_ * 512 * 256;
  if (idx < total) {
    int k = idx & 255;
    int n = (idx >> 8) & 511;
    int h = idx >> 17;
    float w = (n < 256) ? igw[(h*BW + k)*BW + n]
                        : rgw[(h*BW + k)*BW + (n - 256)];
    wt[idx] = f2bf(w);
  }
  if (idx < D_) {
    float z = rp[idx];
    sp[idx] = fmaxf(z, 0.0f) + log1pf(__expf(-fabsf(z)));
  }
}

// Stage one 32KB B-chunk into LDS: chunk g (0..7) covers ig cols [g*32,g*32+32)
// (lds rows 0..31) and rg cols [256+g*32, +32) (lds rows 32..63), full k=256 bf16,
// XOR-swizzled: lds[n*512 + (kb ^ ((n&7)<<4))] = w[col(n)][kb]. The global source
// carries the same XOR so global_load_lds's linear lane*16 write lands right.
__device__ __forceinline__ void stage_chunk(const unsigned short* __restrict__ wth,
                                            unsigned short* Bsm,
                                            int wave, int lane, int g) {
  #pragma unroll
  for (int i = 0; i < 8; ++i) {
    const int ob = wave * 8192 + i * 1024;    // wave-uniform LDS byte base (1KB/call)
    const int o  = ob + lane * 16;            // this lane's LDS byte slot
    const int n  = o >> 9;                    // 0..63
    const int nm = n + ((n < 32) ? g * 32 : 224 + g * 32);  // global weight col
    const int sb = (o & 511) ^ ((n & 7) << 4);              // swizzled k-byte
    async_copy16(wth + (size_t)nm * 256 + (sb >> 1), Bsm + (ob >> 1));
  }
}

// ---------------- gates: block = 4 waves x 32 rows = 128 rows, one head.
// 8 column-chunks of (32 ig | 32 rg); each chunk's 32KB B-tile staged in LDS and
// shared by all 4 waves; each ds_read_b128 feeds 2 MFMAs. A register-resident.
// launch_bounds(256,3): cap ~170 regs — FITS the ~140 this shape needs (r3 lesson:
// a 128 cap spills A-frags to scratch, +230MB FETCH). 3 waves/SIMD, 3 blocks/CU.
// MFMA 16x16x32 bf16. A-frag: A[m=lane&15][k=quad*8+j]; B-frag: B[k=quad*8+j][n=lane&15];
// C/D: col=lane&15, row=quad*4+r.
__global__ __launch_bounds__(256, 3) void gates_kernel(
    const float* __restrict__ act, const int* __restrict__ pos,
    const float* __restrict__ igb, const float* __restrict__ rgb,
    const unsigned short* __restrict__ wt, const float* __restrict__ sp,
    __half2* __restrict__ ax) {
  __shared__ unsigned short Bsm[16384];   // 32 KB
  const int h    = blockIdx.y;
  const int wave = threadIdx.x >> 6;
  const int lane = threadIdx.x & 63;
  const int l15  = lane & 15;
  const int quad = lane >> 4;
  const int m0w  = blockIdx.x * 128 + wave * 32;
  const int hd   = h * BW;
  const unsigned short* wth = wt + (size_t)h * 512 * 256;

  // ---- A fragments: 2 row-tiles x 8 k-tiles (32 rows x 256 k), kept all kernel
  s16x8 A[2][8];
  #pragma unroll
  for (int mt = 0; mt < 2; ++mt) {
    const float* ar = act + (size_t)(m0w + mt * 16 + l15) * D_ + hd;
    #pragma unroll
    for (int kt = 0; kt < 8; ++kt) {
      const int ko = kt * 32 + quad * 8;
      f32x4 f0 = *(const f32x4*)(ar + ko);
      f32x4 f1 = *(const f32x4*)(ar + ko + 4);
      s16x8 af;
      af[0] = (short)f2bf(f0[0]); af[1] = (short)f2bf(f0[1]);
      af[2] = (short)f2bf(f0[2]); af[3] = (short)f2bf(f0[3]);
      af[4] = (short)f2bf(f1[0]); af[5] = (short)f2bf(f1[1]);
      af[6] = (short)f2bf(f1[2]); af[7] = (short)f2bf(f1[3]);
      A[mt][kt] = af;
    }
  }

  bool rst[2][4];
  #pragma unroll
  for (int mt = 0; mt < 2; ++mt)
    #pragma unroll
    for (int r = 0; r < 4; ++r)
      rst[mt][r] = (pos[m0w + mt * 16 + quad * 4 + r] == 0);

  stage_chunk(wth, Bsm, wave, lane, 0);

  for (int g = 0; g < 8; ++g) {
    __syncthreads();   // staging of chunk g complete (vmcnt drained + barrier)

    f32x4 acc[2][4];
    #pragma unroll
    for (int mt = 0; mt < 2; ++mt)
      #pragma unroll
      for (int nq = 0; nq < 4; ++nq)
        acc[mt][nq] = (f32x4){0.f, 0.f, 0.f, 0.f};

    #pragma unroll
    for (int kt = 0; kt < 8; ++kt) {
      #pragma unroll
      for (int nq = 0; nq < 4; ++nq) {
        const int bo = ((nq * 16 + l15) << 9) +
                       (((kt << 6) + (quad << 4)) ^ ((l15 & 7) << 4));
        const s16x8 bf = *(const s16x8*)((const char*)Bsm + bo);
        acc[0][nq] = __builtin_amdgcn_mfma_f32_16x16x32_bf16(A[0][kt], bf, acc[0][nq], 0, 0, 0);
        acc[1][nq] = __builtin_amdgcn_mfma_f32_16x16x32_bf16(A[1][kt], bf, acc[1][nq], 0, 0, 0);
      }
    }

    __syncthreads();   // all waves done reading chunk g
    if (g < 7) stage_chunk(wth, Bsm, wave, lane, g + 1);   // async prefetch

    // epilogue for this 32-col chunk overlaps the async staging above.
    // nq 0..1 = ig accumulators, nq 2..3 = matching rg accumulators (same d).
    #pragma unroll
    for (int nqp = 0; nqp < 2; ++nqp) {
      const int d = hd + g * 32 + nqp * 16 + l15;
      const float bi  = igb[d];
      const float br  = rgb[d];
      const float spd = sp[d];
      #pragma unroll
      for (int mt = 0; mt < 2; ++mt) {
        #pragma unroll
        for (int r = 0; r < 4; ++r) {
          const int row = m0w + mt * 16 + quad * 4 + r;
          const float ig_logit = acc[mt][nqp][r]     + bi;
          const float rg_logit = acc[mt][nqp + 2][r] + br;
          const float igate = 1.0f / (1.0f + __expf(-ig_logit));
          const float rgate = 1.0f / (1.0f + __expf(-rg_logit));
          const float a     = __expf(-8.0f * rgate * spd);
          const bool  rs    = rst[mt][r];
          const float a_eff = rs ? 0.0f : a;
          const float mult  = rs ? 1.0f : sqrtf(fmaxf(1.0f - a * a, 0.0f));
          const float xv    = act[(size_t)row * D_ + d];
          const float xo    = xv * igate * mult;
          ax[(size_t)row * D_ + d] = __float22half2_rn(make_float2(a_eff, xo));
        }
      }
    }
  }
}

// ---------------- scan K1: per-chunk aggregate (P = prod a, X = local scan).
// Streams ax once (8B/thread/t), writes float4 (P0,X0,P1,X1) per thread.
// Aggregate layout: agg[((b*DGK+dg)*CCH + c)*256 + tid] — a (b,dg) column's 64
// chunk-levels are contiguous so K2's compose reads are dense.
__global__ __launch_bounds__(256) void scan_agg_kernel(
    const float2* __restrict__ ax2, float4* __restrict__ agg) {
  const int dpair = blockIdx.x * 256 + threadIdx.x;   // 0..1279
  const int c = blockIdx.y;
  const int b = blockIdx.z;
  const float2* p = ax2 + (size_t)(b * T_ + c * LCH) * DHALF + dpair;
  float P0 = 1.f, X0 = 0.f, P1 = 1.f, X1 = 0.f;
  #pragma unroll 4
  for (int t = 0; t < LCH; ++t) {
    const float2 w = p[(size_t)t * DHALF];
    union { float f; __half2 h; } u0, u1;
    u0.f = w.x; u1.f = w.y;
    const float2 f0 = __half22float2(u0.h);   // (a0, x0)
    const float2 f1 = __half22float2(u1.h);   // (a1, x1)
    X0 = fmaf(f0.x, X0, f0.y);  P0 *= f0.x;
    X1 = fmaf(f1.x, X1, f1.y);  P1 *= f1.x;
  }
  const size_t o = ((size_t)(b * DGK + blockIdx.x) * CCH + c) * 256 + threadIdx.x;
  agg[o] = make_float4(P0, X0, P1, X1);
}

// ---------------- scan K2: compose carry from predecessor aggregates (redundant
// per-block, dense L2-resident reads, NO flags/spinning — kernel boundary gives
// coherence), then replay the chunk streaming ax once and writing out.
__global__ __launch_bounds__(256) void scan_out_kernel(
    const float2* __restrict__ ax2, const float4* __restrict__ agg,
    float2* __restrict__ out2) {
  const int dpair = blockIdx.x * 256 + threadIdx.x;
  const int c = blockIdx.y;
  const int b = blockIdx.z;

  float h0 = 0.f, h1 = 0.f;
  const float4* ag = agg + (size_t)(b * DGK + blockIdx.x) * CCH * 256 + threadIdx.x;
  for (int j = 0; j < c; ++j) {          // ascending — same order as old scanB
    const float4 a = ag[(size_t)j * 256];
    h0 = fmaf(a.x, h0, a.y);
    h1 = fmaf(a.z, h1, a.w);
  }

  const size_t base = (size_t)(b * T_ + c * LCH) * DHALF + dpair;
  #pragma unroll 4
  for (int t = 0; t < LCH; ++t) {
    const float2 w = ax2[base + (size_t)t * DHALF];
    union { float f; __half2 h; } u0, u1;
    u0.f = w.x; u1.f = w.y;
    const float2 f0 = __half22float2(u0.h);
    const float2 f1 = __half22float2(u1.h);
    h0 = fmaf(f0.x, h0, f0.y);
    h1 = fmaf(f1.x, h1, f1.y);
    out2[base + (size_t)t * DHALF] = make_float2(h0, h1);
  }
}

extern "C" void kernel_launch(void* const* d_in, const int* in_sizes, int n_in,
                              void* d_out, int out_size, void* d_ws, size_t ws_size,
                              hipStream_t stream) {
  const float* act = (const float*)d_in[0];
  const int*   pos = (const int*)d_in[1];
  const float* igw = (const float*)d_in[2];
  const float* igb = (const float*)d_in[3];
  const float* rgw = (const float*)d_in[4];
  const float* rgb = (const float*)d_in[5];
  const float* rp  = (const float*)d_in[6];
  float* out = (float*)d_out;

  char* ws = (char*)d_ws;
  __half2* ax = (__half2*)ws;               ws += (size_t)B_ * T_ * D_ * 4;
  unsigned short* wt = (unsigned short*)ws; ws += (size_t)H_ * 512 * 256 * 2;
  float* sp = (float*)ws;                   ws += 4096;                      // D_*4 padded
  float4* agg = (float4*)ws;                ws += (size_t)B_ * DGK * CCH * 256 * 16;

  prep_kernel<<<dim3((H_ * 512 * 256 + 255) / 256), 256, 0, stream>>>(igw, rgw, rp, wt, sp);
  gates_kernel<<<dim3(NROWS / 128, H_), 256, 0, stream>>>(act, pos, igb, rgb, wt, sp, ax);
  scan_agg_kernel<<<dim3(DGK, CCH, B_), 256, 0, stream>>>((const float2*)ax, agg);
  scan_out_kernel<<<dim3(DGK, CCH, B_), 256, 0, stream>>>((const float2*)ax, agg, (float2*)out);
}